// Round 1
// baseline (209.553 us; speedup 1.0000x reference)
//
#include <hip/hip_runtime.h>
#include <hip/hip_bf16.h>

// Problem: B=8192 rows, N=64 nodes, C=256. Per node: MLP 1->C->C->1 on s=Q*Y,
// then softmax over [z0, z_1..z_64] per row. Output f32 [B, 65].

#define BM 128
#define BK 64

typedef __attribute__((ext_vector_type(8))) short bf16x8;
typedef __attribute__((ext_vector_type(4))) float f32x4;

__device__ __forceinline__ unsigned short f2bf(float f) {
    unsigned int u = __float_as_uint(f);
    u += 0x7FFFu + ((u >> 16) & 1u);   // RNE
    return (unsigned short)(u >> 16);
}

// ---------------------------------------------------------------------------
// Kernel 0: W2 [N][C][D] f32  ->  W2t [N][D][C] bf16 (so MFMA B-operand reads
// are K(=c)-contiguous). LDS-tiled 32x32 transpose for coalescing both sides.
// ---------------------------------------------------------------------------
__global__ __launch_bounds__(256) void transpose_w2(
    const float* __restrict__ W2, unsigned short* __restrict__ W2t)
{
    __shared__ float tile[32][33];
    const int n  = blockIdx.z;
    const int c0 = blockIdx.y << 5;
    const int d0 = blockIdx.x << 5;
    const int tx = threadIdx.x & 31;
    const int ty = threadIdx.x >> 5;   // 0..7
    const float* src = W2 + ((size_t)n << 16);
    #pragma unroll
    for (int j = 0; j < 32; j += 8)
        tile[ty + j][tx] = src[(size_t)(c0 + ty + j) * 256 + d0 + tx];
    __syncthreads();
    unsigned short* dst = W2t + ((size_t)n << 16);
    #pragma unroll
    for (int j = 0; j < 32; j += 8)
        dst[(size_t)(d0 + ty + j) * 256 + c0 + tx] = f2bf(tile[tx][ty + j]);
}

// ---------------------------------------------------------------------------
// Kernel 1: per (batch-tile, node) fused MLP. Computes H1 on the fly into LDS,
// GEMM H1[128,256] x W2[256,256] via mfma_f32_16x16x32_bf16, fused epilogue
// (bias2+relu, dot W3, +b3) -> Z[b][n] f32 logits.
// 8 waves: wave (wr,wc) owns a 64x64 output sub-tile, acc 4x4 frags.
// LDS XOR-swizzle on both tiles: short_idx ^ ((row&7)<<3) (row stride 128B
// would otherwise be a 16-way bank conflict on ds_read_b128).
// ---------------------------------------------------------------------------
__global__ __launch_bounds__(512) void gemm_node(
    const float* __restrict__ Q, const float* __restrict__ Y,
    const float* __restrict__ W1, const float* __restrict__ b1,
    const unsigned short* __restrict__ W2t,
    const float* __restrict__ b2, const float* __restrict__ W3,
    const float* __restrict__ b3, float* __restrict__ Z)
{
    __shared__ short sA[BM * BK];     // H1 tile, swizzled
    __shared__ short sB[256 * BK];    // W2t tile, swizzled
    __shared__ float zpart[4][BM];

    const int tid  = threadIdx.x;
    const int lane = tid & 63;
    const int wave = tid >> 6;
    const int wr = wave >> 2;         // 0..1 (row half)
    const int wc = wave & 3;          // 0..3 (col quarter)
    const int n  = blockIdx.y;
    const int b0 = blockIdx.x * BM;

    // A-staging assignment: thread -> (row ar, 16-wide k chunk at ak)
    const int ar = tid >> 2;          // 0..127
    const int ak = (tid & 3) << 4;    // 0,16,32,48
    const float sv = Q[(size_t)(b0 + ar) * 64 + n] * Y[(size_t)(b0 + ar) * 64 + n];

    const float* W1n = W1 + n * 256;
    const float* b1n = b1 + n * 256;
    const unsigned short* W2n = W2t + ((size_t)n << 16);

    f32x4 acc[4][4] = {};

    for (int k0 = 0; k0 < 256; k0 += BK) {
        // ---- B stage: issue global loads early (4 x 16B per thread) ----
        bf16x8 breg[4];
        #pragma unroll
        for (int i = 0; i < 4; i++) {
            int idx = tid + i * 512;          // 0..2047
            int d   = idx >> 3;               // 0..255
            int kk  = (idx & 7) << 3;         // 0..56
            breg[i] = *reinterpret_cast<const bf16x8*>(&W2n[(size_t)d * 256 + k0 + kk]);
        }
        // ---- A stage: h1 = relu(s*W1 + b1), computed, cvt bf16, swizzled ----
        #pragma unroll
        for (int half = 0; half < 2; half++) {
            const int kb = ak + half * 8;
            float4 w1a = *reinterpret_cast<const float4*>(&W1n[k0 + kb]);
            float4 w1b = *reinterpret_cast<const float4*>(&W1n[k0 + kb + 4]);
            float4 b1a = *reinterpret_cast<const float4*>(&b1n[k0 + kb]);
            float4 b1b = *reinterpret_cast<const float4*>(&b1n[k0 + kb + 4]);
            bf16x8 av;
            av[0] = f2bf(fmaxf(sv * w1a.x + b1a.x, 0.f));
            av[1] = f2bf(fmaxf(sv * w1a.y + b1a.y, 0.f));
            av[2] = f2bf(fmaxf(sv * w1a.z + b1a.z, 0.f));
            av[3] = f2bf(fmaxf(sv * w1a.w + b1a.w, 0.f));
            av[4] = f2bf(fmaxf(sv * w1b.x + b1b.x, 0.f));
            av[5] = f2bf(fmaxf(sv * w1b.y + b1b.y, 0.f));
            av[6] = f2bf(fmaxf(sv * w1b.z + b1b.z, 0.f));
            av[7] = f2bf(fmaxf(sv * w1b.w + b1b.w, 0.f));
            *reinterpret_cast<bf16x8*>(&sA[(ar * BK + kb) ^ ((ar & 7) << 3)]) = av;
        }
        // ---- B write (swizzled) ----
        #pragma unroll
        for (int i = 0; i < 4; i++) {
            int idx = tid + i * 512;
            int d   = idx >> 3;
            int kk  = (idx & 7) << 3;
            *reinterpret_cast<bf16x8*>(&sB[(d * BK + kk) ^ ((d & 7) << 3)]) = breg[i];
        }
        __syncthreads();

        // ---- MFMA: 2 k-slices x 4x4 frags ----
        #pragma unroll
        for (int ks = 0; ks < BK; ks += 32) {
            const int krd = ks + ((lane >> 4) << 3);
            bf16x8 afr[4], bfr[4];
            #pragma unroll
            for (int m = 0; m < 4; m++) {
                int row = (wr << 6) + (m << 4) + (lane & 15);
                afr[m] = *reinterpret_cast<const bf16x8*>(&sA[(row * BK + krd) ^ ((row & 7) << 3)]);
            }
            #pragma unroll
            for (int p = 0; p < 4; p++) {
                int col = (wc << 6) + (p << 4) + (lane & 15);
                bfr[p] = *reinterpret_cast<const bf16x8*>(&sB[(col * BK + krd) ^ ((col & 7) << 3)]);
            }
            #pragma unroll
            for (int m = 0; m < 4; m++)
                #pragma unroll
                for (int p = 0; p < 4; p++)
                    acc[m][p] = __builtin_amdgcn_mfma_f32_16x16x32_bf16(afr[m], bfr[p], acc[m][p], 0, 0, 0);
        }
        __syncthreads();
    }

    // ---- Epilogue: z_partial = sum_d relu(acc + b2[d]) * W3[d] ----
    float w3v[4], b2v[4];
    #pragma unroll
    for (int p = 0; p < 4; p++) {
        int d = (wc << 6) + (p << 4) + (lane & 15);
        w3v[p] = W3[n * 256 + d];
        b2v[p] = b2[n * 256 + d];
    }
    #pragma unroll
    for (int m = 0; m < 4; m++) {
        #pragma unroll
        for (int j = 0; j < 4; j++) {
            float pz = 0.f;
            #pragma unroll
            for (int p = 0; p < 4; p++)
                pz += fmaxf(acc[m][p][j] + b2v[p], 0.f) * w3v[p];
            // reduce across the 16 lanes holding different d (same output row)
            pz += __shfl_xor(pz, 1, 64);
            pz += __shfl_xor(pz, 2, 64);
            pz += __shfl_xor(pz, 4, 64);
            pz += __shfl_xor(pz, 8, 64);
            if ((lane & 15) == 0) {
                int row = (wr << 6) + (m << 4) + ((lane >> 4) << 2) + j;
                zpart[wc][row] = pz;
            }
        }
    }
    __syncthreads();
    if (tid < BM) {
        float z = zpart[0][tid] + zpart[1][tid] + zpart[2][tid] + zpart[3][tid] + b3[n];
        Z[(size_t)(b0 + tid) * 64 + n] = z;
    }
}

// ---------------------------------------------------------------------------
// Kernel 2: per-row 65-way softmax. One wave per batch row; lane l = node l.
// z0 = bias0 - sum(s). relu(softmax) == softmax (positive), so skipped.
// ---------------------------------------------------------------------------
__global__ __launch_bounds__(256) void softmax_rows(
    const float* __restrict__ Q, const float* __restrict__ Y,
    const float* __restrict__ Z, const float* __restrict__ bias0,
    float* __restrict__ out)
{
    const int lane = threadIdx.x & 63;
    const int wv   = threadIdx.x >> 6;
    const int b    = (blockIdx.x << 2) + wv;

    float s = Q[(size_t)b * 64 + lane] * Y[(size_t)b * 64 + lane];
    float ssum = s;
    #pragma unroll
    for (int mask = 32; mask >= 1; mask >>= 1) ssum += __shfl_xor(ssum, mask, 64);
    const float z0 = bias0[0] - ssum;

    float zl = Z[(size_t)b * 64 + lane];
    float mx = zl;
    #pragma unroll
    for (int mask = 32; mask >= 1; mask >>= 1) mx = fmaxf(mx, __shfl_xor(mx, mask, 64));
    mx = fmaxf(mx, z0);

    float el = expf(zl - mx);
    float e0 = expf(z0 - mx);
    float den = el;
    #pragma unroll
    for (int mask = 32; mask >= 1; mask >>= 1) den += __shfl_xor(den, mask, 64);
    den += e0;
    const float inv = 1.0f / den;

    out[(size_t)b * 65 + 1 + lane] = el * inv;
    if (lane == 0) out[(size_t)b * 65] = e0 * inv;
}

// ---------------------------------------------------------------------------
extern "C" void kernel_launch(void* const* d_in, const int* in_sizes, int n_in,
                              void* d_out, int out_size, void* d_ws, size_t ws_size,
                              hipStream_t stream)
{
    const float* Q     = (const float*)d_in[0];
    const float* Y     = (const float*)d_in[1];
    const float* W1    = (const float*)d_in[2];
    const float* b1    = (const float*)d_in[3];
    const float* W2    = (const float*)d_in[4];
    const float* b2    = (const float*)d_in[5];
    const float* W3    = (const float*)d_in[6];
    const float* b3    = (const float*)d_in[7];
    const float* bias0 = (const float*)d_in[8];
    float* out = (float*)d_out;

    // workspace layout: W2t bf16 (8.39 MB) | Z f32 logits (2.10 MB)
    unsigned short* W2t = (unsigned short*)d_ws;
    float* Z = (float*)((char*)d_ws + (size_t)64 * 256 * 256 * 2);

    transpose_w2<<<dim3(8, 8, 64), 256, 0, stream>>>(W2, W2t);
    gemm_node<<<dim3(64, 64), 512, 0, stream>>>(Q, Y, W1, b1, W2t, b2, W3, b3, Z);
    softmax_rows<<<2048, 256, 0, stream>>>(Q, Y, Z, bias0, out);
}